// Round 4
// baseline (392.076 us; speedup 1.0000x reference)
//
#include <hip/hip_runtime.h>

#define T_SEQ   4096
#define DM      1024
#define NB      4
#define ROWS    (NB * T_SEQ)   /* 16384 */
#define NCH     64             /* chunks over time */
#define LCH     (T_SEQ / NCH)  /* 64 steps per chunk */

typedef unsigned short ushort_t;

typedef __attribute__((ext_vector_type(8))) short bf16x8;
typedef __attribute__((ext_vector_type(4))) float f32x4;

__device__ __forceinline__ float bf2f(ushort_t u) {
  return __uint_as_float(((unsigned int)u) << 16);
}
__device__ __forceinline__ ushort_t f2bf(float f) {
  unsigned int u = __float_as_uint(f);
  u += 0x7FFFu + ((u >> 16) & 1u);
  return (ushort_t)(u >> 16);
}

__device__ __forceinline__ void async16(const void* g, void* l) {
  __builtin_amdgcn_global_load_lds(
      (const __attribute__((address_space(1))) unsigned int*)g,
      (__attribute__((address_space(3))) unsigned int*)l, 16, 0, 0);
}

// st_16x32 swizzled byte offset of element (row, col) in a [rows]x64 bf16 tile.
__device__ __forceinline__ int fragoff(int row, int col) {
  int p = (((row >> 4) * 2 + (col >> 5)) << 10) + ((row & 15) << 6) + ((col & 31) << 1);
  return p ^ (((row >> 3) & 1) << 5);
}

// ---------------- f32 -> bf16 conversion (for W matrices, 4 MB each) --------
__global__ __launch_bounds__(256)
void cvt_bf16(const float* __restrict__ in, ushort_t* __restrict__ out, const int n4) {
  const int stride = gridDim.x * blockDim.x;
  for (int i = blockIdx.x * blockDim.x + threadIdx.x; i < n4; i += stride) {
    const float4 f = ((const float4*)in)[i];
    ushort4 o;
    o.x = f2bf(f.x); o.y = f2bf(f.y); o.z = f2bf(f.z); o.w = f2bf(f.w);
    ((ushort4*)out)[i] = o;
  }
}

// ---------------- GEMM 256x256 8-phase: C = A @ W(bf16)^T + bias -------------
// A: [M][K] row-major, f32 (reg-staged + fused cvt) or bf16 (global_load_lds).
// W: [N][K] bf16. 512 thr = 8 waves (2Mx4N), per-wave 128x64. BK=64, dbuf LDS,
// st_16x32 swizzle, counted vmcnt. bf16 C goes through a per-wave LDS bounce
// for coalesced 16B stores; f32 C stores direct (64B segments already).
template <typename AT, typename OutT>
__global__ __launch_bounds__(512, 2)
void gemm256(const AT* __restrict__ A, const ushort_t* __restrict__ W,
             const float* __restrict__ bias, OutT* __restrict__ C,
             const int M, const int N, const int K) {
  constexpr bool A_F32 = sizeof(AT) == 4;
  __shared__ char smem[131072];   // A: 2x32KB @0, B: 2x32KB @65536
  const int T = K >> 6;
  const int nwg = (M >> 8) * (N >> 8);
  const int wg  = ((int)blockIdx.x & 7) * (nwg >> 3) + ((int)blockIdx.x >> 3); // nwg%8==0
  const int ntn = N >> 8;
  const int tm = wg / ntn, tn = wg % ntn;
  const int m0 = tm << 8, n0 = tn << 8;
  const int tid  = threadIdx.x;
  const int lane = tid & 63;
  const int wave = tid >> 6;
  const int wm128 = (wave >> 2) * 128;
  const int wn64  = (wave & 3) * 64;
  const int r15 = lane & 15;
  const int kq8 = (lane >> 4) * 8;

  const float*    Af = (const float*)A;
  const ushort_t* Ab = (const ushort_t*)A;

  // gload_lds staging coords (linear LDS dest -> unswizzled source element)
  int srow[2], scol[2];
  #pragma unroll
  for (int rho = 0; rho < 2; ++rho) {
    int p  = rho * 8192 + tid * 16;
    int pp = p ^ (((p >> 9) & 1) << 5);
    int e  = pp >> 1;
    int S = e >> 9, inr = e & 511;
    srow[rho] = ((S >> 1) << 4) + (inr >> 5);
    scol[rho] = ((S & 1) << 5) + (inr & 31);
  }

  auto stageAg = [&](int tile, int half) {   // bf16 A via global_load_lds
    const int boff = ((tile & 1) << 15) + (half << 14);
    #pragma unroll
    for (int rho = 0; rho < 2; ++rho) {
      const ushort_t* g = Ab + (size_t)(m0 + half * 128 + srow[rho]) * K + (tile << 6) + scol[rho];
      async16(g, &smem[boff + rho * 8192 + tid * 16]);
    }
  };
  auto stageB = [&](int tile, int half) {
    const int boff = 65536 + ((tile & 1) << 15) + (half << 14);
    #pragma unroll
    for (int rho = 0; rho < 2; ++rho) {
      const ushort_t* g = W + (size_t)(n0 + half * 128 + srow[rho]) * K + (tile << 6) + scol[rho];
      async16(g, &smem[boff + rho * 8192 + tid * 16]);
    }
  };

  // f32 A reg-staging: thread covers (row = rho*64 + tid>>3, col8 = (tid&7)*8)
  float4 sA0[2][2], sA1[2][2];
  auto loadA = [&](float4 (&s)[2][2], int tile, int half) {
    #pragma unroll
    for (int rho = 0; rho < 2; ++rho) {
      const int rl = rho * 64 + (tid >> 3);
      const float* g = Af + (size_t)(m0 + half * 128 + rl) * K + (tile << 6) + ((tid & 7) * 8);
      s[rho][0] = *(const float4*)g;
      s[rho][1] = *(const float4*)(g + 4);
    }
  };
  auto writeA = [&](float4 (&s)[2][2], int tile, int half) {
    const int boff = ((tile & 1) << 15) + (half << 14);
    #pragma unroll
    for (int rho = 0; rho < 2; ++rho) {
      const int rl = rho * 64 + (tid >> 3);
      uint4 w;
      w.x = ((unsigned)f2bf(s[rho][0].y) << 16) | f2bf(s[rho][0].x);
      w.y = ((unsigned)f2bf(s[rho][0].w) << 16) | f2bf(s[rho][0].z);
      w.z = ((unsigned)f2bf(s[rho][1].y) << 16) | f2bf(s[rho][1].x);
      w.w = ((unsigned)f2bf(s[rho][1].w) << 16) | f2bf(s[rho][1].z);
      *(uint4*)&smem[boff + fragoff(rl, (tid & 7) * 8)] = w;
    }
  };

  f32x4 acc[8][4];
  #pragma unroll
  for (int i = 0; i < 8; ++i)
    #pragma unroll
    for (int j = 0; j < 4; ++j)
      acc[i][j] = (f32x4){0.f, 0.f, 0.f, 0.f};
  bf16x8 bf[4][2];

  // ---- prologue: tile0 A+B, tile1 B staged; B(1) left in flight ----
  if constexpr (A_F32) {
    loadA(sA0, 0, 0); loadA(sA1, 0, 1);
    stageB(0, 0); stageB(0, 1); stageB(1, 0); stageB(1, 1);
    writeA(sA0, 0, 0); writeA(sA1, 0, 1);      // compiler waits A-load vmcnt
    asm volatile("s_waitcnt vmcnt(4)" ::: "memory");   // B(0) done, B(1) in flight
    asm volatile("s_waitcnt lgkmcnt(0)" ::: "memory"); // ds_writes visible
  } else {
    stageAg(0, 0); stageAg(0, 1);
    stageB(0, 0); stageB(0, 1); stageB(1, 0); stageB(1, 1);
    asm volatile("s_waitcnt vmcnt(4)" ::: "memory");
  }
  __builtin_amdgcn_s_barrier();

#define GPHASE(Q, STG, TAILW)                                                    \
  {                                                                              \
    bf16x8 af[2][2];                                                             \
    _Pragma("unroll") for (int fl = 0; fl < 2; ++fl)                             \
      _Pragma("unroll") for (int ks = 0; ks < 2; ++ks)                           \
        af[fl][ks] = *(const bf16x8*)&smem[abase +                               \
            fragoff(wm128 + ((2 * (Q) + fl) << 4) + r15, (ks << 5) + kq8)];      \
    if ((Q) == 0) {                                                              \
      _Pragma("unroll") for (int fj = 0; fj < 4; ++fj)                           \
        _Pragma("unroll") for (int ks = 0; ks < 2; ++ks)                         \
          bf[fj][ks] = *(const bf16x8*)&smem[bbase +                             \
              fragoff(wn64 + (fj << 4) + r15, (ks << 5) + kq8)];                 \
    }                                                                            \
    STG();                                                                       \
    __builtin_amdgcn_s_barrier();                                                \
    __builtin_amdgcn_s_setprio(1);                                               \
    _Pragma("unroll") for (int fl = 0; fl < 2; ++fl)                             \
      _Pragma("unroll") for (int fj = 0; fj < 4; ++fj)                           \
        _Pragma("unroll") for (int ks = 0; ks < 2; ++ks)                         \
          acc[2 * (Q) + fl][fj] = __builtin_amdgcn_mfma_f32_16x16x32_bf16(       \
              af[fl][ks], bf[fj][ks], acc[2 * (Q) + fl][fj], 0, 0, 0);           \
    __builtin_amdgcn_s_setprio(0);                                               \
    TAILW();                                                                     \
    __builtin_amdgcn_s_barrier();                                                \
  }

  for (int j = 0; j < T; ++j) {
    const int abase = (j & 1) << 15;
    const int bbase = 65536 + ((j & 1) << 15);
    const bool p1 = (j + 1 < T), p2 = (j + 2 < T);
    auto nw = [&] {};
    if constexpr (A_F32) {
      // A(j+1): load@P0/P1, cvt+ds_write@P1/P2. B(j+2): gload_lds@P2/P3.
      // A-slot consumption vmcnt waits also drain older B gloads -> no bwait.
      auto s0 = [&] { if (p1) loadA(sA0, j + 1, 0); };
      auto s1 = [&] { if (p1) { loadA(sA1, j + 1, 1); writeA(sA0, j + 1, 0); } };
      auto s2 = [&] { if (p2) stageB(j + 2, 0); if (p1) writeA(sA1, j + 1, 1); };
      auto s3 = [&] { if (p2) stageB(j + 2, 1); };
      GPHASE(0, s0, nw);
      GPHASE(1, s1, nw);
      GPHASE(2, s2, nw);
      GPHASE(3, s3, nw);
    } else {
      auto s0 = [&] { if (p1) stageAg(j + 1, 0); };
      auto s1 = [&] { if (p1) stageAg(j + 1, 1); };
      auto s2 = [&] { if (p2) stageB(j + 2, 0); };
      auto s3 = [&] { if (p2) stageB(j + 2, 1); };
      auto bwait = [&] {
        if (p2) asm volatile("s_waitcnt vmcnt(4)" ::: "memory");
        else    asm volatile("s_waitcnt vmcnt(0)" ::: "memory");
      };
      GPHASE(0, s0, nw);
      GPHASE(1, s1, nw);
      GPHASE(2, s2, nw);
      GPHASE(3, s3, bwait);
    }
  }
#undef GPHASE

  // ---- epilogue. C/D layout: col = lane&15, row = (lane>>4)*4 + reg ----
  float bias4[4];
  #pragma unroll
  for (int fj = 0; fj < 4; ++fj) bias4[fj] = bias[n0 + wn64 + fj * 16 + r15];

  if constexpr (sizeof(OutT) == 2) {
    // per-wave 4KB LDS bounce -> coalesced 16B bf16 stores
    const int wbase = wave * 4096;
    #pragma unroll
    for (int fi = 0; fi < 8; ++fi) {
      #pragma unroll
      for (int fj = 0; fj < 4; ++fj)
        #pragma unroll
        for (int r = 0; r < 4; ++r) {
          const int row = (lane >> 4) * 4 + r;
          const int col = fj * 16 + r15;
          *(ushort_t*)&smem[wbase + (row * 64 + col) * 2] = f2bf(acc[fi][fj][r] + bias4[fj]);
        }
      #pragma unroll
      for (int round = 0; round < 2; ++round) {
        const uint4 q = *(const uint4*)&smem[wbase + round * 1024 + lane * 16];
        const int rl   = round * 8 + (lane >> 3);
        const int col8 = (lane & 7) * 8;
        *(uint4*)&C[(size_t)(m0 + wm128 + fi * 16 + rl) * N + n0 + wn64 + col8] = q;
      }
    }
  } else {
    #pragma unroll
    for (int fi = 0; fi < 8; ++fi) {
      const int row0 = m0 + wm128 + fi * 16 + (lane >> 4) * 4;
      #pragma unroll
      for (int fj = 0; fj < 4; ++fj) {
        const int col = n0 + wn64 + fj * 16 + r15;
        #pragma unroll
        for (int r = 0; r < 4; ++r)
          C[(size_t)(row0 + r) * N + col] = acc[fi][fj][r] + bias4[fj];
      }
    }
  }
}

// ---------------- WKV chunked scan ------------------------------------------
__global__ __launch_bounds__(256)
void wkv_pass1(const ushort_t* __restrict__ kp, const ushort_t* __restrict__ vp,
               const float* __restrict__ decay,
               float* __restrict__ s_num, float* __restrict__ s_den) {
  const int tid = threadIdx.x;
  const int grp = blockIdx.x & 3;
  const int c   = (blockIdx.x >> 2) & (NCH - 1);
  const int b   = (int)blockIdx.x >> 8;
  const int ch  = grp * 256 + tid;
  const float df = __expf(-__expf(decay[ch]));
  size_t idx = (size_t)b * T_SEQ * DM + (size_t)(c * LCH) * DM + ch;
  float num = 0.f, den = 0.f;
  for (int u = 0; u < LCH; ++u, idx += DM) {
    float kf = bf2f(kp[idx]);
    kf = fminf(fmaxf(kf, -10.f), 10.f);
    const float ek = __expf(kf);
    const float vv = bf2f(vp[idx]);
    num = fmaf(num, df, ek * vv);
    den = fmaf(den, df, ek);
  }
  const size_t si = ((size_t)b * NCH + c) * DM + ch;
  s_num[si] = num;
  s_den[si] = den;
}

__global__ __launch_bounds__(256)
void wkv_pass2(const float* __restrict__ decay,
               float* __restrict__ s_num, float* __restrict__ s_den) {
  const int tid = threadIdx.x;
  const int grp = blockIdx.x & 3;
  const int b   = (int)blockIdx.x >> 2;
  const int ch  = grp * 256 + tid;
  const float dfL = __expf(-__expf(decay[ch]) * (float)LCH);
  float an = 0.f, ad = 0.f;
  size_t si = (size_t)b * NCH * DM + ch;
  for (int c = 0; c < NCH; ++c, si += DM) {
    const float ln = s_num[si], ld = s_den[si];
    s_num[si] = an; s_den[si] = ad;
    an = fmaf(an, dfL, ln);
    ad = fmaf(ad, dfL, ld);
  }
}

__global__ __launch_bounds__(256)
void wkv_pass3(const ushort_t* __restrict__ kp, const ushort_t* __restrict__ vp,
               const ushort_t* __restrict__ rp, const float* __restrict__ decay,
               const float* __restrict__ bonus,
               const float* __restrict__ s_num, const float* __restrict__ s_den,
               ushort_t* __restrict__ G) {
  const int tid = threadIdx.x;
  const int grp = blockIdx.x & 3;
  const int c   = (blockIdx.x >> 2) & (NCH - 1);
  const int b   = (int)blockIdx.x >> 8;
  const int ch  = grp * 256 + tid;
  const float df = __expf(-__expf(decay[ch]));
  const float eb = __expf(bonus[ch]);
  const size_t si = ((size_t)b * NCH + c) * DM + ch;
  float num = s_num[si], den = s_den[si];
  size_t idx = (size_t)b * T_SEQ * DM + (size_t)(c * LCH) * DM + ch;
  for (int u = 0; u < LCH; ++u, idx += DM) {
    float kf = bf2f(kp[idx]);
    kf = fminf(fmaxf(kf, -10.f), 10.f);
    const float ek = __expf(kf);
    const float bw = eb * ek;
    const float vv = bf2f(vp[idx]);
    const float rr = bf2f(rp[idx]);
    const float numer = fmaf(bw, vv, num);
    const float denom = den + bw + 1e-6f;
    const float wkv = numer * __builtin_amdgcn_rcpf(denom);
    const float sig = __builtin_amdgcn_rcpf(1.f + __expf(-rr));
    G[idx] = f2bf(sig * wkv);
    num = fmaf(num, df, ek * vv);
    den = fmaf(den, df, ek);
  }
}

// ---------------- launch -----------------------------------------------------
extern "C" void kernel_launch(void* const* d_in, const int* in_sizes, int n_in,
                              void* d_out, int out_size, void* d_ws, size_t ws_size,
                              hipStream_t stream) {
  const float* q   = (const float*)d_in[0];
  const float* ky  = (const float*)d_in[1];
  const float* vl  = (const float*)d_in[2];
  const float* Wr  = (const float*)d_in[3];
  const float* br  = (const float*)d_in[4];
  const float* Wk  = (const float*)d_in[5];
  const float* bk  = (const float*)d_in[6];
  const float* Wv  = (const float*)d_in[7];
  const float* bv  = (const float*)d_in[8];
  const float* Wo  = (const float*)d_in[9];
  const float* bo  = (const float*)d_in[10];
  const float* decay = (const float*)d_in[11];
  const float* bonus = (const float*)d_in[12];
  float* out = (float*)d_out;

  const size_t NE = (size_t)ROWS * DM;
  const size_t WE = (size_t)DM * DM;

  ushort_t* xb = (ushort_t*)d_ws;        // G lives here (A-staging no longer needed)
  ushort_t* wb = xb + NE;                // W bf16 (2 MB), aliased by scan summaries
  ushort_t* rp = wb + WE;
  ushort_t* kp = rp + NE;
  ushort_t* vp = kp + NE;
  ushort_t* G  = xb;
  float* s_num = (float*)wb;
  float* s_den = s_num + (size_t)NB * NCH * DM;

  const int w4 = (int)(WE / 4);
  dim3 cB(256), gW(1024);
  dim3 gemmGrid((ROWS / 256) * (DM / 256)), gemmBlk(512);
  dim3 scanGrid(NB * NCH * (DM / 256)), scanBlk(256);

  // r projection (A = q, f32 fused-cvt staging)
  cvt_bf16<<<gW, cB, 0, stream>>>(Wr, wb, w4);
  gemm256<float, ushort_t><<<gemmGrid, gemmBlk, 0, stream>>>(q, wb, br, rp, ROWS, DM, DM);
  // k projection
  cvt_bf16<<<gW, cB, 0, stream>>>(Wk, wb, w4);
  gemm256<float, ushort_t><<<gemmGrid, gemmBlk, 0, stream>>>(ky, wb, bk, kp, ROWS, DM, DM);
  // v projection
  cvt_bf16<<<gW, cB, 0, stream>>>(Wv, wb, w4);
  gemm256<float, ushort_t><<<gemmGrid, gemmBlk, 0, stream>>>(vl, wb, bv, vp, ROWS, DM, DM);
  // WKV chunk-parallel scan + gate -> G (bf16); summaries alias wb (free now)
  wkv_pass1<<<scanGrid, scanBlk, 0, stream>>>(kp, vp, decay, s_num, s_den);
  wkv_pass2<<<dim3(NB * DM / 256), scanBlk, 0, stream>>>(decay, s_num, s_den);
  wkv_pass3<<<scanGrid, scanBlk, 0, stream>>>(kp, vp, rp, decay, bonus, s_num, s_den, G);
  // output projection (A = G bf16 via gload_lds, f32 out)
  cvt_bf16<<<gW, cB, 0, stream>>>(Wo, wb, w4);
  gemm256<ushort_t, float><<<gemmGrid, gemmBlk, 0, stream>>>(G, wb, bo, out, ROWS, DM, DM);
}

// Round 6
// 258.768 us; speedup vs baseline: 1.5152x; 1.5152x over previous
//
#include <hip/hip_runtime.h>

#define T_SEQ   4096
#define DM      1024
#define NB      4
#define ROWS    (NB * T_SEQ)   /* 16384 */
#define NCH     64             /* chunks over time */
#define LCH     (T_SEQ / NCH)  /* 64 steps per chunk */

typedef unsigned short ushort_t;

typedef __attribute__((ext_vector_type(8))) short bf16x8;
typedef __attribute__((ext_vector_type(4))) float f32x4;

__device__ __forceinline__ float bf2f(ushort_t u) {
  return __uint_as_float(((unsigned int)u) << 16);
}
__device__ __forceinline__ ushort_t f2bf(float f) {
  unsigned int u = __float_as_uint(f);
  u += 0x7FFFu + ((u >> 16) & 1u);
  return (ushort_t)(u >> 16);
}
__device__ __forceinline__ unsigned cvtpk(float lo, float hi) {
  unsigned r;
  asm("v_cvt_pk_bf16_f32 %0, %1, %2" : "=v"(r) : "v"(lo), "v"(hi));
  return r;
}

__device__ __forceinline__ void async16(const void* g, void* l) {
  __builtin_amdgcn_global_load_lds(
      (const __attribute__((address_space(1))) unsigned int*)g,
      (__attribute__((address_space(3))) unsigned int*)l, 16, 0, 0);
}

// st_16x32 swizzled byte offset of (row,col) in a [rows]x64 bf16 tile.
__device__ __forceinline__ int fragoff(int row, int col) {
  int p = (((row >> 4) * 2 + (col >> 5)) << 10) + ((row & 15) << 6) + ((col & 31) << 1);
  return p ^ (((row >> 3) & 1) << 5);
}
// swizzled byte offset of (row,col) in a [rows]x32 bf16 tile (subtile 16x32).
__device__ __forceinline__ int fragoffB32(int row, int col) {
  int p = ((row >> 4) << 10) + ((row & 15) << 6) + (col << 1);
  return p ^ (((row >> 3) & 1) << 5);
}
// swizzled byte offset of (row,col) in a [rows]x32 f32 tile (subtile 8x32).
__device__ __forceinline__ int fragoffA32f(int row, int col) {
  int p = ((row >> 3) << 10) + ((row & 7) << 7) + (col << 2);
  return p ^ ((row & 7) << 4);
}

// ---------------- W cvt + bias pack (one launch) ----------------------------
__global__ __launch_bounds__(256)
void cvt_pack(const float* __restrict__ Wr, const float* __restrict__ Wk,
              const float* __restrict__ Wv, const float* __restrict__ Wo,
              const float* __restrict__ br, const float* __restrict__ bk,
              const float* __restrict__ bv, const float* __restrict__ bo,
              ushort_t* __restrict__ wb, float* __restrict__ biasP) {
  const int bid = blockIdx.x;
  if (bid < 2048) {
    const int n4 = (DM * DM);              // 4 matrices * WE/4 groups
    for (int i = bid * 256 + threadIdx.x; i < n4; i += 2048 * 256) {
      const int seg = i >> 18;             // WE/4 = 2^18
      const float* src = seg == 0 ? Wr : seg == 1 ? Wk : seg == 2 ? Wv : Wo;
      const float4 f = ((const float4*)src)[i & 262143];
      ushort4 o;
      o.x = f2bf(f.x); o.y = f2bf(f.y); o.z = f2bf(f.z); o.w = f2bf(f.w);
      ((ushort4*)wb)[i] = o;
    }
  } else {
    const int s = bid - 2048;
    const float* b = s == 0 ? br : s == 1 ? bk : s == 2 ? bv : bo;
    for (int i = threadIdx.x; i < DM; i += 256) biasP[s * DM + i] = b[i];
  }
}

// ---------------- GEMM 256x256 (R3-proven, bf16 A via gload_lds) -------------
template <typename OutT>
__global__ __launch_bounds__(512, 2)
void gemm256(const ushort_t* __restrict__ A, const ushort_t* __restrict__ W,
             const float* __restrict__ bias, OutT* __restrict__ C,
             const int M, const int N, const int K) {
  __shared__ char smem[131072];   // A: 2x32KB @0, B: 2x32KB @65536
  const int T = K >> 6;
  const int nwg = (M >> 8) * (N >> 8);
  const int wg  = ((int)blockIdx.x & 7) * (nwg >> 3) + ((int)blockIdx.x >> 3);
  const int ntn = N >> 8;
  const int tm = wg / ntn, tn = wg % ntn;
  const int m0 = tm << 8, n0 = tn << 8;
  const int tid  = threadIdx.x;
  const int lane = tid & 63;
  const int wave = tid >> 6;
  const int wm128 = (wave >> 2) * 128;
  const int wn64  = (wave & 3) * 64;
  const int r15 = lane & 15;
  const int kq8 = (lane >> 4) * 8;

  int srow[2], scol[2];
  #pragma unroll
  for (int rho = 0; rho < 2; ++rho) {
    int p  = rho * 8192 + tid * 16;
    int pp = p ^ (((p >> 9) & 1) << 5);
    int e  = pp >> 1;
    int S = e >> 9, inr = e & 511;
    srow[rho] = ((S >> 1) << 4) + (inr >> 5);
    scol[rho] = ((S & 1) << 5) + (inr & 31);
  }

  auto stageA = [&](int tile, int half) {
    const int boff = ((tile & 1) << 15) + (half << 14);
    #pragma unroll
    for (int rho = 0; rho < 2; ++rho) {
      const ushort_t* g = A + (size_t)(m0 + half * 128 + srow[rho]) * K + (tile << 6) + scol[rho];
      async16(g, &smem[boff + rho * 8192 + tid * 16]);
    }
  };
  auto stageB = [&](int tile, int half) {
    const int boff = 65536 + ((tile & 1) << 15) + (half << 14);
    #pragma unroll
    for (int rho = 0; rho < 2; ++rho) {
      const ushort_t* g = W + (size_t)(n0 + half * 128 + srow[rho]) * K + (tile << 6) + scol[rho];
      async16(g, &smem[boff + rho * 8192 + tid * 16]);
    }
  };

  f32x4 acc[8][4];
  #pragma unroll
  for (int i = 0; i < 8; ++i)
    #pragma unroll
    for (int j = 0; j < 4; ++j)
      acc[i][j] = (f32x4){0.f, 0.f, 0.f, 0.f};
  bf16x8 bf[4][2];

  stageA(0, 0); stageA(0, 1); stageB(0, 0); stageB(0, 1); stageB(1, 0); stageB(1, 1);
  asm volatile("s_waitcnt vmcnt(4)" ::: "memory");
  __builtin_amdgcn_s_barrier();

#define GPHASE(Q, STG, TAILW)                                                    \
  {                                                                              \
    bf16x8 af[2][2];                                                             \
    _Pragma("unroll") for (int fl = 0; fl < 2; ++fl)                             \
      _Pragma("unroll") for (int ks = 0; ks < 2; ++ks)                           \
        af[fl][ks] = *(const bf16x8*)&smem[abase +                               \
            fragoff(wm128 + ((2 * (Q) + fl) << 4) + r15, (ks << 5) + kq8)];      \
    if ((Q) == 0) {                                                              \
      _Pragma("unroll") for (int fj = 0; fj < 4; ++fj)                           \
        _Pragma("unroll") for (int ks = 0; ks < 2; ++ks)                         \
          bf[fj][ks] = *(const bf16x8*)&smem[bbase +                             \
              fragoff(wn64 + (fj << 4) + r15, (ks << 5) + kq8)];                 \
    }                                                                            \
    STG();                                                                       \
    __builtin_amdgcn_s_barrier();                                                \
    __builtin_amdgcn_s_setprio(1);                                               \
    _Pragma("unroll") for (int fl = 0; fl < 2; ++fl)                             \
      _Pragma("unroll") for (int fj = 0; fj < 4; ++fj)                           \
        _Pragma("unroll") for (int ks = 0; ks < 2; ++ks)                         \
          acc[2 * (Q) + fl][fj] = __builtin_amdgcn_mfma_f32_16x16x32_bf16(       \
              af[fl][ks], bf[fj][ks], acc[2 * (Q) + fl][fj], 0, 0, 0);           \
    __builtin_amdgcn_s_setprio(0);                                               \
    TAILW();                                                                     \
    __builtin_amdgcn_s_barrier();                                                \
  }

  for (int j = 0; j < T; ++j) {
    const int abase = (j & 1) << 15;
    const int bbase = 65536 + ((j & 1) << 15);
    const bool p1 = (j + 1 < T), p2 = (j + 2 < T);
    auto s0 = [&] { if (p1) stageA(j + 1, 0); };
    auto s1 = [&] { if (p1) stageA(j + 1, 1); };
    auto s2 = [&] { if (p2) stageB(j + 2, 0); };
    auto s3 = [&] { if (p2) stageB(j + 2, 1); };
    auto nw = [&] {};
    auto bwait = [&] {
      if (p2) asm volatile("s_waitcnt vmcnt(4)" ::: "memory");
      else    asm volatile("s_waitcnt vmcnt(0)" ::: "memory");
    };
    GPHASE(0, s0, nw);
    GPHASE(1, s1, nw);
    GPHASE(2, s2, nw);
    GPHASE(3, s3, bwait);
  }
#undef GPHASE

  float bias4[4];
  #pragma unroll
  for (int fj = 0; fj < 4; ++fj) bias4[fj] = bias[n0 + wn64 + fj * 16 + r15];
  #pragma unroll
  for (int fi = 0; fi < 8; ++fi) {
    const int row0 = m0 + wm128 + fi * 16 + (lane >> 4) * 4;
    #pragma unroll
    for (int fj = 0; fj < 4; ++fj) {
      const int col = n0 + wn64 + fj * 16 + r15;
      #pragma unroll
      for (int r = 0; r < 4; ++r) {
        const float v = acc[fi][fj][r] + bias4[fj];
        if constexpr (sizeof(OutT) == 2) C[(size_t)(row0 + r) * N + col] = f2bf(v);
        else                             C[(size_t)(row0 + r) * N + col] = v;
      }
    }
  }
}

// ---------------- grouped projection GEMM: f32 A direct ----------------------
// grid 768 = 3 matrices x 256 tiles. BK=32. A staged f32 via global_load_lds
// (inverse-swizzled source), converted to bf16 on ds_read via v_cvt_pk_bf16_f32.
__global__ __launch_bounds__(512, 2)
void gemm256_proj(const float* __restrict__ Aq, const float* __restrict__ Ak,
                  const float* __restrict__ Av, const ushort_t* __restrict__ Wb,
                  const float* __restrict__ biasP, ushort_t* __restrict__ Cb,
                  const int M, const int N, const int K) {
  __shared__ char smem[98304];    // A f32: 2x32KB @0, B bf16: 2x16KB @65536
  const int T = K >> 5;           // BK=32
  const int wg = ((int)blockIdx.x & 7) * 96 + ((int)blockIdx.x >> 3); // nwg=768
  const int g  = wg >> 8;
  const int local = wg & 255;
  const int ntn = N >> 8;         // 4
  const int tm = local / ntn, tn = local % ntn;
  const int m0 = tm << 8, n0 = tn << 8;
  const float*    Af = g == 0 ? Aq : (g == 1 ? Ak : Av);
  const ushort_t* W  = Wb + (size_t)g * N * K;
  const float*  bias = biasP + g * N;
  ushort_t*        C = Cb + (size_t)g * M * N;

  const int tid  = threadIdx.x;
  const int lane = tid & 63;
  const int wave = tid >> 6;
  const int wm128 = (wave >> 2) * 128;
  const int wn64  = (wave & 3) * 64;
  const int r15 = lane & 15;
  const int kq8 = (lane >> 4) * 8;

  // A staging (f32): per half (128 rows x 32 f32 = 16KB), thread covers 2x16B
  int arow[2], acol[2];
  #pragma unroll
  for (int rho = 0; rho < 2; ++rho) {
    const int p = rho * 8192 + tid * 16;
    const int e = p ^ (((p >> 7) & 7) << 4);
    arow[rho] = ((p >> 10) << 3) | ((p >> 7) & 7);
    acol[rho] = (e >> 2) & 31;
  }
  // B staging (bf16): per half (128 rows x 32 bf16 = 8KB), thread covers 1x16B
  int brow, bcol;
  {
    const int p = tid * 16;
    const int pp = p ^ (((p >> 9) & 1) << 5);
    const int e = pp >> 1;
    brow = ((e >> 9) << 4) | ((e >> 5) & 15);
    bcol = e & 31;
  }

  auto stageA = [&](int tile, int half) {
    const int boff = ((tile & 1) << 15) + (half << 14);
    #pragma unroll
    for (int rho = 0; rho < 2; ++rho) {
      const float* g2 = Af + (size_t)(m0 + half * 128 + arow[rho]) * K + (tile << 5) + acol[rho];
      async16(g2, &smem[boff + rho * 8192 + tid * 16]);
    }
  };
  auto stageB = [&](int tile, int half) {
    const int boff = 65536 + ((tile & 1) << 14) + (half << 13);
    const ushort_t* g2 = W + (size_t)(n0 + half * 128 + brow) * K + (tile << 5) + bcol;
    async16(g2, &smem[boff + tid * 16]);
  };

  auto rdA = [&](int abase, int row) -> bf16x8 {
    // NOTE: hi half is at fragoffA32f(row, kq8+4) == lo ^ 16 (NOT lo + 16:
    // for odd rows the swizzle already sets bit4 and +16 carries into bit5).
    const int adlo = abase + fragoffA32f(row, kq8);
    const int adhi = abase + fragoffA32f(row, kq8 + 4);
    const f32x4 lo = *(const f32x4*)&smem[adlo];
    const f32x4 hi = *(const f32x4*)&smem[adhi];
    union { uint4 u4; bf16x8 b; } cv;
    cv.u4.x = cvtpk(lo[0], lo[1]); cv.u4.y = cvtpk(lo[2], lo[3]);
    cv.u4.z = cvtpk(hi[0], hi[1]); cv.u4.w = cvtpk(hi[2], hi[3]);
    return cv.b;
  };

  f32x4 acc[8][4];
  #pragma unroll
  for (int i = 0; i < 8; ++i)
    #pragma unroll
    for (int j = 0; j < 4; ++j)
      acc[i][j] = (f32x4){0.f, 0.f, 0.f, 0.f};
  bf16x8 bf[4];

  // prologue: A(0) [4 loads] + B(0) [2] + B(1) [2]; keep B(1) in flight
  stageA(0, 0); stageA(0, 1); stageB(0, 0); stageB(0, 1); stageB(1, 0); stageB(1, 1);
  asm volatile("s_waitcnt vmcnt(2)" ::: "memory");
  __builtin_amdgcn_s_barrier();

#define PPHASE(Q, STG, TAILW)                                                    \
  {                                                                              \
    bf16x8 af[2];                                                                \
    _Pragma("unroll") for (int fl = 0; fl < 2; ++fl)                             \
      af[fl] = rdA(abase, wm128 + ((2 * (Q) + fl) << 4) + r15);                  \
    if ((Q) == 0) {                                                              \
      _Pragma("unroll") for (int fj = 0; fj < 4; ++fj)                           \
        bf[fj] = *(const bf16x8*)&smem[bbase +                                   \
            fragoffB32(wn64 + (fj << 4) + r15, kq8)];                            \
    }                                                                            \
    STG();                                                                       \
    __builtin_amdgcn_s_barrier();                                                \
    __builtin_amdgcn_s_setprio(1);                                               \
    _Pragma("unroll") for (int fl = 0; fl < 2; ++fl)                             \
      _Pragma("unroll") for (int fj = 0; fj < 4; ++fj)                           \
        acc[2 * (Q) + fl][fj] = __builtin_amdgcn_mfma_f32_16x16x32_bf16(         \
            af[fl], bf[fj], acc[2 * (Q) + fl][fj], 0, 0, 0);                     \
    __builtin_amdgcn_s_setprio(0);                                               \
    TAILW();                                                                     \
    __builtin_amdgcn_s_barrier();                                                \
  }

  for (int j = 0; j < T; ++j) {
    const int abase = (j & 1) << 15;
    const int bbase = 65536 + ((j & 1) << 14);
    const bool p1 = (j + 1 < T), p2 = (j + 2 < T);
    auto s0 = [&] { if (p1) stageA(j + 1, 0); };
    auto s1 = [&] { if (p1) stageA(j + 1, 1); };
    auto s2 = [&] { if (p2) { stageB(j + 2, 0); stageB(j + 2, 1); } };
    auto nw = [&] {};
    auto bwait = [&] {
      if (p2) asm volatile("s_waitcnt vmcnt(2)" ::: "memory");
      else    asm volatile("s_waitcnt vmcnt(0)" ::: "memory");
    };
    PPHASE(0, s0, nw);
    PPHASE(1, s1, nw);
    PPHASE(2, s2, nw);
    PPHASE(3, nw, bwait);
  }
#undef PPHASE

  float bias4[4];
  #pragma unroll
  for (int fj = 0; fj < 4; ++fj) bias4[fj] = bias[n0 + wn64 + fj * 16 + r15];
  #pragma unroll
  for (int fi = 0; fi < 8; ++fi) {
    const int row0 = m0 + wm128 + fi * 16 + (lane >> 4) * 4;
    #pragma unroll
    for (int fj = 0; fj < 4; ++fj) {
      const int col = n0 + wn64 + fj * 16 + r15;
      #pragma unroll
      for (int r = 0; r < 4; ++r)
        C[(size_t)(row0 + r) * N + col] = f2bf(acc[fi][fj][r] + bias4[fj]);
    }
  }
}

// ---------------- WKV chunked scan ------------------------------------------
__global__ __launch_bounds__(256)
void wkv_pass1(const ushort_t* __restrict__ kp, const ushort_t* __restrict__ vp,
               const float* __restrict__ decay,
               float* __restrict__ s_num, float* __restrict__ s_den) {
  const int tid = threadIdx.x;
  const int grp = blockIdx.x & 3;
  const int c   = (blockIdx.x >> 2) & (NCH - 1);
  const int b   = (int)blockIdx.x >> 8;
  const int ch  = grp * 256 + tid;
  const float df = __expf(-__expf(decay[ch]));
  size_t idx = (size_t)b * T_SEQ * DM + (size_t)(c * LCH) * DM + ch;
  float num = 0.f, den = 0.f;
  for (int u = 0; u < LCH; ++u, idx += DM) {
    float kf = bf2f(kp[idx]);
    kf = fminf(fmaxf(kf, -10.f), 10.f);
    const float ek = __expf(kf);
    const float vv = bf2f(vp[idx]);
    num = fmaf(num, df, ek * vv);
    den = fmaf(den, df, ek);
  }
  const size_t si = ((size_t)b * NCH + c) * DM + ch;
  s_num[si] = num;
  s_den[si] = den;
}

__global__ __launch_bounds__(256)
void wkv_pass2(const float* __restrict__ decay,
               float* __restrict__ s_num, float* __restrict__ s_den) {
  const int tid = threadIdx.x;
  const int grp = blockIdx.x & 3;
  const int b   = (int)blockIdx.x >> 2;
  const int ch  = grp * 256 + tid;
  const float dfL = __expf(-__expf(decay[ch]) * (float)LCH);
  float an = 0.f, ad = 0.f;
  size_t si = (size_t)b * NCH * DM + ch;
  for (int c = 0; c < NCH; ++c, si += DM) {
    const float ln = s_num[si], ld = s_den[si];
    s_num[si] = an; s_den[si] = ad;
    an = fmaf(an, dfL, ln);
    ad = fmaf(ad, dfL, ld);
  }
}

// rg: r projection IN, gated output OUT (same buffer — per-index read precedes
// write in the same thread; rp is regenerated by the proj GEMM every launch).
__global__ __launch_bounds__(256)
void wkv_pass3(const ushort_t* __restrict__ kp, const ushort_t* __restrict__ vp,
               ushort_t* rg, const float* __restrict__ decay,
               const float* __restrict__ bonus,
               const float* __restrict__ s_num, const float* __restrict__ s_den) {
  const int tid = threadIdx.x;
  const int grp = blockIdx.x & 3;
  const int c   = (blockIdx.x >> 2) & (NCH - 1);
  const int b   = (int)blockIdx.x >> 8;
  const int ch  = grp * 256 + tid;
  const float df = __expf(-__expf(decay[ch]));
  const float eb = __expf(bonus[ch]);
  const size_t si = ((size_t)b * NCH + c) * DM + ch;
  float num = s_num[si], den = s_den[si];
  size_t idx = (size_t)b * T_SEQ * DM + (size_t)(c * LCH) * DM + ch;
  for (int u = 0; u < LCH; ++u, idx += DM) {
    float kf = bf2f(kp[idx]);
    kf = fminf(fmaxf(kf, -10.f), 10.f);
    const float ek = __expf(kf);
    const float bw = eb * ek;
    const float vv = bf2f(vp[idx]);
    const float rr = bf2f(rg[idx]);
    const float numer = fmaf(bw, vv, num);
    const float denom = den + bw + 1e-6f;
    const float wkv = numer * __builtin_amdgcn_rcpf(denom);
    const float sig = __builtin_amdgcn_rcpf(1.f + __expf(-rr));
    rg[idx] = f2bf(sig * wkv);
    num = fmaf(num, df, ek * vv);
    den = fmaf(den, df, ek);
  }
}

// ---------------- launch -----------------------------------------------------
extern "C" void kernel_launch(void* const* d_in, const int* in_sizes, int n_in,
                              void* d_out, int out_size, void* d_ws, size_t ws_size,
                              hipStream_t stream) {
  const float* q   = (const float*)d_in[0];
  const float* ky  = (const float*)d_in[1];
  const float* vl  = (const float*)d_in[2];
  const float* Wr  = (const float*)d_in[3];
  const float* br  = (const float*)d_in[4];
  const float* Wk  = (const float*)d_in[5];
  const float* bk  = (const float*)d_in[6];
  const float* Wv  = (const float*)d_in[7];
  const float* bv  = (const float*)d_in[8];
  const float* Wo  = (const float*)d_in[9];
  const float* bo  = (const float*)d_in[10];
  const float* decay = (const float*)d_in[11];
  const float* bonus = (const float*)d_in[12];
  float* out = (float*)d_out;

  const size_t NE = (size_t)ROWS * DM;   // 16,777,216
  const size_t WE = (size_t)DM * DM;     // 1,048,576

  // ws layout (~111 MB): [wb 8MB][biasP 16KB][rp/G 32MB][kp 32MB][vp 32MB][s_num][s_den]
  ushort_t* wb = (ushort_t*)d_ws;        // packed W: [r,k,v,o][1024][1024] bf16
  float* biasP = (float*)(wb + 4 * WE);  // packed bias: [r,k,v,o][1024]
  ushort_t* rp = (ushort_t*)(biasP + 4 * DM);
  ushort_t* kp = rp + NE;
  ushort_t* vp = kp + NE;
  float* s_num = (float*)(vp + NE);
  float* s_den = s_num + (size_t)NB * NCH * DM;
  ushort_t* G  = rp;                     // gated output overwrites r in place

  dim3 cB(256);
  dim3 gemmGrid((ROWS / 256) * (DM / 256)), gemmBlk(512);
  dim3 projGrid(3 * (ROWS / 256) * (DM / 256));
  dim3 scanGrid(NB * NCH * (DM / 256)), scanBlk(256);

  // pack all W (bf16) + biases in one launch
  cvt_pack<<<dim3(2052), cB, 0, stream>>>(Wr, Wk, Wv, Wo, br, bk, bv, bo, wb, biasP);
  // grouped r/k/v projections, f32 A read direct (no X cvt kernels)
  gemm256_proj<<<projGrid, gemmBlk, 0, stream>>>(q, ky, vl, wb, biasP, rp, ROWS, DM, DM);
  // WKV chunk-parallel scan + gate -> G (in place over rp)
  wkv_pass1<<<scanGrid, scanBlk, 0, stream>>>(kp, vp, decay, s_num, s_den);
  wkv_pass2<<<dim3(NB * DM / 256), scanBlk, 0, stream>>>(decay, s_num, s_den);
  wkv_pass3<<<scanGrid, scanBlk, 0, stream>>>(kp, vp, rp, decay, bonus, s_num, s_den);
  // output projection (A = G bf16 via gload_lds, f32 out)
  gemm256<float><<<gemmGrid, gemmBlk, 0, stream>>>(G, wb + 3 * WE, biasP + 3 * DM, out, ROWS, DM, DM);
}

// Round 7
// 254.446 us; speedup vs baseline: 1.5409x; 1.0170x over previous
//
#include <hip/hip_runtime.h>

#define T_SEQ   4096
#define DM      1024
#define NB      4
#define ROWS    (NB * T_SEQ)   /* 16384 */
#define NCH     64             /* chunks over time */
#define LCH     (T_SEQ / NCH)  /* 64 steps per chunk */

typedef unsigned short ushort_t;

typedef __attribute__((ext_vector_type(8))) short bf16x8;
typedef __attribute__((ext_vector_type(4))) float f32x4;

__device__ __forceinline__ float bf2f(ushort_t u) {
  return __uint_as_float(((unsigned int)u) << 16);
}
__device__ __forceinline__ ushort_t f2bf(float f) {
  unsigned int u = __float_as_uint(f);
  u += 0x7FFFu + ((u >> 16) & 1u);
  return (ushort_t)(u >> 16);
}
__device__ __forceinline__ unsigned cvtpk(float lo, float hi) {
  unsigned r;
  asm("v_cvt_pk_bf16_f32 %0, %1, %2" : "=v"(r) : "v"(lo), "v"(hi));
  return r;
}

__device__ __forceinline__ void async16(const void* g, void* l) {
  __builtin_amdgcn_global_load_lds(
      (const __attribute__((address_space(1))) unsigned int*)g,
      (__attribute__((address_space(3))) unsigned int*)l, 16, 0, 0);
}

// swizzled byte offset of (row,col) in a [rows]x32 bf16 tile (subtile 16x32).
__device__ __forceinline__ int fragoffB32(int row, int col) {
  int p = ((row >> 4) << 10) + ((row & 15) << 6) + (col << 1);
  return p ^ (((row >> 3) & 1) << 5);
}
// swizzled byte offset of (row,col) in a [rows]x32 f32 tile (subtile 8x32).
__device__ __forceinline__ int fragoffA32f(int row, int col) {
  int p = ((row >> 3) << 10) + ((row & 7) << 7) + (col << 2);
  return p ^ ((row & 7) << 4);
}

// ---------------- W cvt + bias pack (one launch) ----------------------------
__global__ __launch_bounds__(256)
void cvt_pack(const float* __restrict__ Wr, const float* __restrict__ Wk,
              const float* __restrict__ Wv, const float* __restrict__ Wo,
              const float* __restrict__ br, const float* __restrict__ bk,
              const float* __restrict__ bv, const float* __restrict__ bo,
              ushort_t* __restrict__ wb, float* __restrict__ biasP) {
  const int bid = blockIdx.x;
  if (bid < 2048) {
    const int n4 = (DM * DM);              // 4 matrices * WE/4 groups
    for (int i = bid * 256 + threadIdx.x; i < n4; i += 2048 * 256) {
      const int seg = i >> 18;             // WE/4 = 2^18
      const float* src = seg == 0 ? Wr : seg == 1 ? Wk : seg == 2 ? Wv : Wo;
      const float4 f = ((const float4*)src)[i & 262143];
      ushort4 o;
      o.x = f2bf(f.x); o.y = f2bf(f.y); o.z = f2bf(f.z); o.w = f2bf(f.w);
      ((ushort4*)wb)[i] = o;
    }
  } else {
    const int s = bid - 2048;
    const float* b = s == 0 ? br : s == 1 ? bk : s == 2 ? bv : bo;
    for (int i = threadIdx.x; i < DM; i += 256) biasP[s * DM + i] = b[i];
  }
}

// ---------------- unified 3-stage GEMM: C = A @ W(bf16)^T + bias -------------
// BM=BN=256, BK=32, 512 thr = 8 waves (2Mx4N), per-wave 128x64.
// Triple-buffered LDS; stage tile j+2 during iter j; one counted vmcnt per
// K-tile (6 for f32-A, 4 for bf16-A) -> ~2-iteration issue-to-consume depth.
// A is f32 (staged f32 via gload_lds, cvt_pk at ds_read) or bf16 (gload_lds).
template <typename AT, typename OutT, int GROUPS>
__global__ __launch_bounds__(512, 2)
void gemm3(const AT* __restrict__ A0, const AT* __restrict__ A1,
           const AT* __restrict__ A2, const ushort_t* __restrict__ Wb,
           const float* __restrict__ biasP, OutT* __restrict__ Cb,
           const int M, const int N, const int K) {
  constexpr bool A_F32 = sizeof(AT) == 4;
  constexpr int ABYTES = A_F32 ? 32768 : 16384;   // 256 x 32 per buffer
  constexpr int BBYTES = 16384;                   // 256 x 32 bf16
  constexpr int AL = A_F32 ? 4 : 2;               // A loads/thread/tile
  __shared__ char smem[3 * (ABYTES + BBYTES)];

  const int T = K >> 5;
  const int ntpg = (M >> 8) * (N >> 8);
  const int nwg  = GROUPS * ntpg;
  const int wg   = ((int)blockIdx.x & 7) * (nwg >> 3) + ((int)blockIdx.x >> 3);
  const int g     = wg / ntpg;
  const int local = wg % ntpg;
  const int ntn = N >> 8;
  const int tm = local / ntn, tn = local % ntn;
  const int m0 = tm << 8, n0 = tn << 8;
  const AT*       Ag   = g == 0 ? A0 : (g == 1 ? A1 : A2);
  const ushort_t* W    = Wb + (size_t)g * N * K;
  const float*    bias = biasP + g * N;
  OutT*           C    = Cb + (size_t)g * M * N;

  const int tid  = threadIdx.x;
  const int lane = tid & 63;
  const int wave = tid >> 6;
  const int wm128 = (wave >> 2) * 128;
  const int wn64  = (wave & 3) * 64;
  const int r15 = lane & 15;
  const int kq8 = (lane >> 4) * 8;

  // staging source coords (linear LDS dest -> unswizzled source element)
  int arow[AL], acol[AL];
  #pragma unroll
  for (int rho = 0; rho < AL; ++rho) {
    const int p = rho * 8192 + tid * 16;
    if constexpr (A_F32) {
      arow[rho] = ((p >> 10) << 3) | ((p >> 7) & 7);
      acol[rho] = ((p ^ (((p >> 7) & 7) << 4)) >> 2) & 31;
    } else {
      const int e = (p ^ (((p >> 9) & 1) << 5)) >> 1;
      arow[rho] = ((e >> 9) << 4) | ((e >> 5) & 15);
      acol[rho] = e & 31;
    }
  }
  int brow[2], bcol[2];
  #pragma unroll
  for (int rho = 0; rho < 2; ++rho) {
    const int p = rho * 8192 + tid * 16;
    const int e = (p ^ (((p >> 9) & 1) << 5)) >> 1;
    brow[rho] = ((e >> 9) << 4) | ((e >> 5) & 15);
    bcol[rho] = e & 31;
  }

  auto stageA = [&](int tile) {
    const int boff = (tile % 3) * ABYTES;
    #pragma unroll
    for (int rho = 0; rho < AL; ++rho) {
      const AT* g2 = Ag + (size_t)(m0 + arow[rho]) * K + (tile << 5) + acol[rho];
      async16(g2, &smem[boff + rho * 8192 + tid * 16]);
    }
  };
  auto stageB = [&](int tile) {
    const int boff = 3 * ABYTES + (tile % 3) * BBYTES;
    #pragma unroll
    for (int rho = 0; rho < 2; ++rho) {
      const ushort_t* g2 = W + (size_t)(n0 + brow[rho]) * K + (tile << 5) + bcol[rho];
      async16(g2, &smem[boff + rho * 8192 + tid * 16]);
    }
  };

  auto rdAfrag = [&](int abase, int row) -> bf16x8 {
    if constexpr (A_F32) {
      // hi half at fragoffA32f(row,kq8+4) (XOR-adjacent slot, NOT +16)
      const f32x4 lo = *(const f32x4*)&smem[abase + fragoffA32f(row, kq8)];
      const f32x4 hi = *(const f32x4*)&smem[abase + fragoffA32f(row, kq8 + 4)];
      union { uint4 u4; bf16x8 b; } cv;
      cv.u4.x = cvtpk(lo[0], lo[1]); cv.u4.y = cvtpk(lo[2], lo[3]);
      cv.u4.z = cvtpk(hi[0], hi[1]); cv.u4.w = cvtpk(hi[2], hi[3]);
      return cv.b;
    } else {
      return *(const bf16x8*)&smem[abase + fragoffB32(row, kq8)];
    }
  };

  f32x4 acc[8][4];
  #pragma unroll
  for (int i = 0; i < 8; ++i)
    #pragma unroll
    for (int j = 0; j < 4; ++j)
      acc[i][j] = (f32x4){0.f, 0.f, 0.f, 0.f};
  bf16x8 bfr[4];

  // prologue: tiles 0,1 staged; wait tile 0 complete (tile 1 in flight)
  stageA(0); stageB(0); stageA(1); stageB(1);
  if constexpr (A_F32) asm volatile("s_waitcnt vmcnt(6)" ::: "memory");
  else                 asm volatile("s_waitcnt vmcnt(4)" ::: "memory");
  __builtin_amdgcn_s_barrier();

#define PH3(H, STG, TAILW)                                                       \
  {                                                                              \
    bf16x8 af[4];                                                                \
    _Pragma("unroll") for (int q = 0; q < 4; ++q)                                \
      af[q] = rdAfrag(curA, wm128 + (H) * 64 + q * 16 + r15);                    \
    if ((H) == 0) {                                                              \
      _Pragma("unroll") for (int fj = 0; fj < 4; ++fj)                           \
        bfr[fj] = *(const bf16x8*)&smem[curB +                                   \
            fragoffB32(wn64 + (fj << 4) + r15, kq8)];                            \
    }                                                                            \
    STG();                                                                       \
    __builtin_amdgcn_s_barrier();                                                \
    __builtin_amdgcn_s_setprio(1);                                               \
    _Pragma("unroll") for (int q = 0; q < 4; ++q)                                \
      _Pragma("unroll") for (int fj = 0; fj < 4; ++fj)                           \
        acc[(H) * 4 + q][fj] = __builtin_amdgcn_mfma_f32_16x16x32_bf16(          \
            af[q], bfr[fj], acc[(H) * 4 + q][fj], 0, 0, 0);                      \
    __builtin_amdgcn_s_setprio(0);                                               \
    TAILW();                                                                     \
    __builtin_amdgcn_s_barrier();                                                \
  }

  for (int j = 0; j < T; ++j) {
    const int curA = (j % 3) * ABYTES;
    const int curB = 3 * ABYTES + (j % 3) * BBYTES;
    const bool p1 = (j + 1 < T), p2 = (j + 2 < T);
    auto sA = [&] { if (p2) stageA(j + 2); };
    auto sB = [&] { if (p2) stageB(j + 2); };
    auto nw = [&] {};
    auto tw = [&] {
      if (!p1) return;
      if (p2) {
        if constexpr (A_F32) asm volatile("s_waitcnt vmcnt(6)" ::: "memory");
        else                 asm volatile("s_waitcnt vmcnt(4)" ::: "memory");
      } else {
        asm volatile("s_waitcnt vmcnt(0)" ::: "memory");
      }
    };
    PH3(0, sA, nw);
    PH3(1, sB, tw);
  }
#undef PH3

  // epilogue. C/D layout: col = lane&15, row = (lane>>4)*4 + reg
  float bias4[4];
  #pragma unroll
  for (int fj = 0; fj < 4; ++fj) bias4[fj] = bias[n0 + wn64 + fj * 16 + r15];
  #pragma unroll
  for (int fi = 0; fi < 8; ++fi) {
    const int row0 = m0 + wm128 + fi * 16 + (lane >> 4) * 4;
    #pragma unroll
    for (int fj = 0; fj < 4; ++fj) {
      const int col = n0 + wn64 + fj * 16 + r15;
      #pragma unroll
      for (int r = 0; r < 4; ++r) {
        const float v = acc[fi][fj][r] + bias4[fj];
        if constexpr (sizeof(OutT) == 2) C[(size_t)(row0 + r) * N + col] = f2bf(v);
        else                             C[(size_t)(row0 + r) * N + col] = v;
      }
    }
  }
}

// ---------------- WKV chunked scan ------------------------------------------
__global__ __launch_bounds__(256)
void wkv_pass1(const ushort_t* __restrict__ kp, const ushort_t* __restrict__ vp,
               const float* __restrict__ decay,
               float* __restrict__ s_num, float* __restrict__ s_den) {
  const int tid = threadIdx.x;
  const int grp = blockIdx.x & 3;
  const int c   = (blockIdx.x >> 2) & (NCH - 1);
  const int b   = (int)blockIdx.x >> 8;
  const int ch  = grp * 256 + tid;
  const float df = __expf(-__expf(decay[ch]));
  size_t idx = (size_t)b * T_SEQ * DM + (size_t)(c * LCH) * DM + ch;
  float num = 0.f, den = 0.f;
  for (int u = 0; u < LCH; ++u, idx += DM) {
    float kf = bf2f(kp[idx]);
    kf = fminf(fmaxf(kf, -10.f), 10.f);
    const float ek = __expf(kf);
    const float vv = bf2f(vp[idx]);
    num = fmaf(num, df, ek * vv);
    den = fmaf(den, df, ek);
  }
  const size_t si = ((size_t)b * NCH + c) * DM + ch;
  s_num[si] = num;
  s_den[si] = den;
}

__global__ __launch_bounds__(256)
void wkv_pass2(const float* __restrict__ decay,
               float* __restrict__ s_num, float* __restrict__ s_den) {
  const int tid = threadIdx.x;
  const int grp = blockIdx.x & 3;
  const int b   = (int)blockIdx.x >> 2;
  const int ch  = grp * 256 + tid;
  const float dfL = __expf(-__expf(decay[ch]) * (float)LCH);
  float an = 0.f, ad = 0.f;
  size_t si = (size_t)b * NCH * DM + ch;
  for (int c = 0; c < NCH; ++c, si += DM) {
    const float ln = s_num[si], ld = s_den[si];
    s_num[si] = an; s_den[si] = ad;
    an = fmaf(an, dfL, ln);
    ad = fmaf(ad, dfL, ld);
  }
}

// rg: r projection IN, gated output OUT (same buffer — per-index read precedes
// write in the same thread; rp is regenerated by the proj GEMM every launch).
__global__ __launch_bounds__(256)
void wkv_pass3(const ushort_t* __restrict__ kp, const ushort_t* __restrict__ vp,
               ushort_t* rg, const float* __restrict__ decay,
               const float* __restrict__ bonus,
               const float* __restrict__ s_num, const float* __restrict__ s_den) {
  const int tid = threadIdx.x;
  const int grp = blockIdx.x & 3;
  const int c   = (blockIdx.x >> 2) & (NCH - 1);
  const int b   = (int)blockIdx.x >> 8;
  const int ch  = grp * 256 + tid;
  const float df = __expf(-__expf(decay[ch]));
  const float eb = __expf(bonus[ch]);
  const size_t si = ((size_t)b * NCH + c) * DM + ch;
  float num = s_num[si], den = s_den[si];
  size_t idx = (size_t)b * T_SEQ * DM + (size_t)(c * LCH) * DM + ch;
  for (int u = 0; u < LCH; ++u, idx += DM) {
    float kf = bf2f(kp[idx]);
    kf = fminf(fmaxf(kf, -10.f), 10.f);
    const float ek = __expf(kf);
    const float bw = eb * ek;
    const float vv = bf2f(vp[idx]);
    const float rr = bf2f(rg[idx]);
    const float numer = fmaf(bw, vv, num);
    const float denom = den + bw + 1e-6f;
    const float wkv = numer * __builtin_amdgcn_rcpf(denom);
    const float sig = __builtin_amdgcn_rcpf(1.f + __expf(-rr));
    rg[idx] = f2bf(sig * wkv);
    num = fmaf(num, df, ek * vv);
    den = fmaf(den, df, ek);
  }
}

// ---------------- launch -----------------------------------------------------
extern "C" void kernel_launch(void* const* d_in, const int* in_sizes, int n_in,
                              void* d_out, int out_size, void* d_ws, size_t ws_size,
                              hipStream_t stream) {
  const float* q   = (const float*)d_in[0];
  const float* ky  = (const float*)d_in[1];
  const float* vl  = (const float*)d_in[2];
  const float* Wr  = (const float*)d_in[3];
  const float* br  = (const float*)d_in[4];
  const float* Wk  = (const float*)d_in[5];
  const float* bk  = (const float*)d_in[6];
  const float* Wv  = (const float*)d_in[7];
  const float* bv  = (const float*)d_in[8];
  const float* Wo  = (const float*)d_in[9];
  const float* bo  = (const float*)d_in[10];
  const float* decay = (const float*)d_in[11];
  const float* bonus = (const float*)d_in[12];
  float* out = (float*)d_out;

  const size_t NE = (size_t)ROWS * DM;   // 16,777,216
  const size_t WE = (size_t)DM * DM;     // 1,048,576

  // ws layout (~111 MB): [wb 8MB][biasP 16KB][rp/G 32MB][kp 32MB][vp 32MB][s_num][s_den]
  ushort_t* wb = (ushort_t*)d_ws;        // packed W: [r,k,v,o][1024][1024] bf16
  float* biasP = (float*)(wb + 4 * WE);  // packed bias: [r,k,v,o][1024]
  ushort_t* rp = (ushort_t*)(biasP + 4 * DM);
  ushort_t* kp = rp + NE;
  ushort_t* vp = kp + NE;
  float* s_num = (float*)(vp + NE);
  float* s_den = s_num + (size_t)NB * NCH * DM;
  ushort_t* G  = rp;                     // gated output overwrites r in place

  dim3 cB(256);
  dim3 gemmBlk(512);
  dim3 projGrid(3 * (ROWS / 256) * (DM / 256));
  dim3 gemmGrid((ROWS / 256) * (DM / 256));
  dim3 scanGrid(NB * NCH * (DM / 256)), scanBlk(256);

  // pack all W (bf16) + biases in one launch
  cvt_pack<<<dim3(2052), cB, 0, stream>>>(Wr, Wk, Wv, Wo, br, bk, bv, bo, wb, biasP);
  // grouped r/k/v projections, f32 A read direct, 3-stage pipeline
  gemm3<float, ushort_t, 3><<<projGrid, gemmBlk, 0, stream>>>(
      q, ky, vl, wb, biasP, rp, ROWS, DM, DM);
  // WKV chunk-parallel scan + gate -> G (in place over rp)
  wkv_pass1<<<scanGrid, scanBlk, 0, stream>>>(kp, vp, decay, s_num, s_den);
  wkv_pass2<<<dim3(NB * DM / 256), scanBlk, 0, stream>>>(decay, s_num, s_den);
  wkv_pass3<<<scanGrid, scanBlk, 0, stream>>>(kp, vp, rp, decay, bonus, s_num, s_den);
  // output projection (A = G bf16 via gload_lds, f32 out), 3-stage pipeline
  gemm3<ushort_t, float, 1><<<gemmGrid, gemmBlk, 0, stream>>>(
      G, G, G, wb + 3 * WE, biasP + 3 * DM, out, ROWS, DM, DM);
}